// Round 2
// baseline (447.931 us; speedup 1.0000x reference)
//
#include <hip/hip_runtime.h>
#include <hip/hip_bf16.h>

typedef unsigned short u16;
typedef unsigned int u32;
typedef __bf16 bf16x8 __attribute__((ext_vector_type(8)));
typedef float f32x4 __attribute__((ext_vector_type(4)));

// ---------- helpers ----------
__device__ __forceinline__ float bf2f(u16 u) {
    u32 x = ((u32)u) << 16;
    return __builtin_bit_cast(float, x);
}
__device__ __forceinline__ u16 f2bf(float f) {
    u32 x = __builtin_bit_cast(u32, f);
    u32 r = (x + 0x7fffu + ((x >> 16) & 1u)) >> 16;  // RNE
    return (u16)r;
}
// delu(x) = 10*relu(x) + exp(10*min(x,0)) = x>0 ? 10x+1 : exp(10x)
__device__ __forceinline__ float delu(float x) {
    return x > 0.f ? fmaf(10.f, x, 1.f) : __expf(10.f * x);
}

// ---------- kernel A: fp32 -> bf16 for x, qkv_w; zero reduction buffers ----------
__global__ __launch_bounds__(256) void convert_all(
    const float4* __restrict__ x, const float4* __restrict__ wq,
    u16* __restrict__ xb, u16* __restrict__ wqb, float* __restrict__ red)
{
    const int NX = 3145728, NQ = 442368;
    int gid = blockIdx.x * blockDim.x + threadIdx.x;
    if (gid < 9216) red[gid] = 0.f;  // k_sum | kv_diag | l_kv_diag
    int stride = gridDim.x * blockDim.x;
    for (int i = gid; i < NX + NQ; i += stride) {
        const float4* src; u16* dst; int li;
        if (i < NX) { src = x;  dst = xb;  li = i; }
        else        { src = wq; dst = wqb; li = i - NX; }
        float4 f = src[li];
        ushort4 u;
        u.x = f2bf(f.x); u.y = f2bf(f.y); u.z = f2bf(f.z); u.w = f2bf(f.w);
        *(ushort4*)&dst[4 * (size_t)li] = u;
    }
}

// ---------- GEMM core: C[m,n] = sum_k A[m,k]*Bt[n,k], 128x128 tile, BK=32 ----------
// LDS per tile: [quad][row][8 bf16] so fragment reads are lane-contiguous
// ds_read_b128 and global_load_lds dest is wave-uniform-base + lane*16.
__device__ __forceinline__ void gemm_core(
    const u16* __restrict__ A, const u16* __restrict__ Bt,
    int K, int m0, int n0, u16* ldsA, u16* ldsB, f32x4 acc[4][4])
{
    const int tid  = threadIdx.x;
    const int lane = tid & 63;
    const int wave = tid >> 6;
    const int wm = wave >> 1, wn = wave & 1;
    const int quad = lane >> 4, r = lane & 15;

    for (int kt = 0; kt < K; kt += 32) {
#pragma unroll
        for (int it = 0; it < 2; ++it) {
            int c   = wave + 4 * it;           // chunk 0..7, wave-uniform
            int q_  = c >> 1;                  // k-quad of this chunk
            int row = ((c & 1) << 6) + lane;   // tile row 0..127
            const u16* ga = A  + (size_t)(m0 + row) * K + kt + q_ * 8;
            const u16* gb = Bt + (size_t)(n0 + row) * K + kt + q_ * 8;
            __builtin_amdgcn_global_load_lds(
                (const __attribute__((address_space(1))) u32*)(const void*)ga,
                (__attribute__((address_space(3))) u32*)(void*)&ldsA[c * 512], 16, 0, 0);
            __builtin_amdgcn_global_load_lds(
                (const __attribute__((address_space(1))) u32*)(const void*)gb,
                (__attribute__((address_space(3))) u32*)(void*)&ldsB[c * 512], 16, 0, 0);
        }
        __syncthreads();
        bf16x8 af[4], bfr[4];
#pragma unroll
        for (int i = 0; i < 4; ++i)
            af[i] = *(const bf16x8*)&ldsA[quad * 1024 + (wm * 64 + i * 16 + r) * 8];
#pragma unroll
        for (int j = 0; j < 4; ++j)
            bfr[j] = *(const bf16x8*)&ldsB[quad * 1024 + (wn * 64 + j * 16 + r) * 8];
#pragma unroll
        for (int i = 0; i < 4; ++i)
#pragma unroll
            for (int j = 0; j < 4; ++j)
                acc[i][j] = __builtin_amdgcn_mfma_f32_16x16x32_bf16(
                    af[i], bfr[j], acc[i][j], 0, 0, 0);
        __syncthreads();
    }
}

// ---------- kernel B: qkv GEMM, delu on q,k cols, bf16 out ----------
__global__ __launch_bounds__(256) void gemm_qkv(
    const u16* __restrict__ A, const u16* __restrict__ Bt, u16* __restrict__ C)
{
    __shared__ u16 ldsA[4096], ldsB[4096];
    f32x4 acc[4][4] = {};
    const int m0 = blockIdx.y * 128, n0 = blockIdx.x * 128;
    gemm_core(A, Bt, 768, m0, n0, ldsA, ldsB, acc);

    const int lane = threadIdx.x & 63;
    const int wave = threadIdx.x >> 6;
    const int wm = wave >> 1, wn = wave & 1;
    const int l15 = lane & 15, l4 = lane >> 4;
#pragma unroll
    for (int i = 0; i < 4; ++i) {
#pragma unroll
        for (int j = 0; j < 4; ++j) {
            int col = n0 + wn * 64 + j * 16 + l15;
            int row = m0 + wm * 64 + i * 16 + l4 * 4;
            bool isqk = col < 1536;  // q,k get delu; v passes through
#pragma unroll
            for (int rr = 0; rr < 4; ++rr) {
                float v = acc[i][j][rr];
                if (isqk) v = delu(v);
                C[(size_t)(row + rr) * 2304 + col] = f2bf(v);
            }
        }
    }
}

// ---------- kernel C: reductions over N -> k_sum, kv_diag, l_kv_diag (B,H,D) ----------
__global__ __launch_bounds__(256) void reduce_kv(
    const u16* __restrict__ qkv, const float* __restrict__ y,
    float* __restrict__ ksum, float* __restrict__ kvd, float* __restrict__ lkvd)
{
    int blk = blockIdx.x;
    int b = blk / 192, rem = blk % 192;
    int h = rem >> 4, chunk = rem & 15;
    int t = threadIdx.x;
    int d2 = t & 31, sub = t >> 5;
    int col = h * 64 + 2 * d2;

    float s_k0 = 0, s_k1 = 0, s_kv0 = 0, s_kv1 = 0, s_l0 = 0, s_l1 = 0;
    for (int i = 0; i < 32; ++i) {
        int n = chunk * 256 + sub + 8 * i;
        size_t row = (size_t)(b << 12) + n;
        u32 kk = *(const u32*)&qkv[row * 2304 + 768 + col];
        u32 vv = *(const u32*)&qkv[row * 2304 + 1536 + col];
        float2 yy = *(const float2*)&y[row * 768 + col];
        float k0 = bf2f((u16)(kk & 0xffff)), k1 = bf2f((u16)(kk >> 16));
        float v0 = bf2f((u16)(vv & 0xffff)), v1 = bf2f((u16)(vv >> 16));
        float l0 = delu(yy.x), l1 = delu(yy.y);
        s_k0 += k0;                       s_k1 += k1;
        s_kv0 = fmaf(k0, v0, s_kv0);      s_kv1 = fmaf(k1, v1, s_kv1);
        s_l0  = fmaf(l0, v0, s_l0);       s_l1  = fmaf(l1, v1, s_l1);
    }
    __shared__ float red[256][6];
    red[t][0] = s_k0; red[t][1] = s_k1; red[t][2] = s_kv0;
    red[t][3] = s_kv1; red[t][4] = s_l0; red[t][5] = s_l1;
    __syncthreads();
    if (t < 32) {
        float a0 = red[t][0], a1 = red[t][1], a2 = red[t][2];
        float a3 = red[t][3], a4 = red[t][4], a5 = red[t][5];
        for (int s = 1; s < 8; ++s) {
            a0 += red[t + 32 * s][0]; a1 += red[t + 32 * s][1];
            a2 += red[t + 32 * s][2]; a3 += red[t + 32 * s][3];
            a4 += red[t + 32 * s][4]; a5 += red[t + 32 * s][5];
        }
        int bh = b * 12 + h;
        int d = 2 * t;
        atomicAdd(&ksum[bh * 64 + d],     a0);
        atomicAdd(&ksum[bh * 64 + d + 1], a1);
        atomicAdd(&kvd[bh * 64 + d],      a2 * 0.125f);
        atomicAdd(&kvd[bh * 64 + d + 1],  a3 * 0.125f);
        atomicAdd(&lkvd[bh * 64 + d],     a4 * 0.125f);
        atomicAdd(&lkvd[bh * 64 + d + 1], a5 * 0.125f);
    }
}

// ---------- kernel D: fold kv_diag / l_kv_diag into per-batch scaled weights ----------
// w1s[b][o][c] = w1[o][c] * kvd[b, c>>6, c&63]   (bf16), same for w2s/lkvd.
__global__ __launch_bounds__(256) void scale_weights(
    const float* __restrict__ w1, const float* __restrict__ w2,
    const float* __restrict__ kvd, const float* __restrict__ lkvd,
    u16* __restrict__ w1s, u16* __restrict__ w2s)
{
    const int NITEM = 1179648;  // 2 tensors * 4 batches * 768 * 192 quads
    int gid = blockIdx.x * blockDim.x + threadIdx.x;
    int stride = gridDim.x * blockDim.x;
    for (int i = gid; i < NITEM; i += stride) {
        int t = i / 589824, r = i % 589824;
        int b = r / 147456, rr = r % 147456;
        int o = rr / 192, c = (rr % 192) * 4;
        const float* w = t ? w2 : w1;
        const float* dg = t ? lkvd : kvd;
        u16* dst = t ? w2s : w1s;
        float4 wf = *(const float4*)&w[o * 768 + c];
        float4 sf = *(const float4*)&dg[(b * 12 + (c >> 6)) * 64 + (c & 63)];
        ushort4 u;
        u.x = f2bf(wf.x * sf.x); u.y = f2bf(wf.y * sf.y);
        u.z = f2bf(wf.z * sf.z); u.w = f2bf(wf.w * sf.w);
        *(ushort4*)&dst[(size_t)b * 589824 + o * 768 + c] = u;
    }
}

// ---------- kernel E: q' = q * norm  (bf16) ----------
// block = 768 threads = 12 waves; wave == head; lane == d channel.
__global__ __launch_bounds__(768) void norm_q(
    const u16* __restrict__ qkv, const float* __restrict__ ksum,
    u16* __restrict__ qn)
{
    int row = blockIdx.x;
    int c = threadIdx.x;
    int h = c >> 6, d = c & 63;
    int b = row >> 12;
    int bh = b * 12 + h;
    float qf = bf2f(qkv[(size_t)row * 2304 + c]);   // q (already delu'd)
    float ks = ksum[bh * 64 + d] + 1e-10f;
    float p = qf * ks;
#pragma unroll
    for (int off = 32; off; off >>= 1) p += __shfl_xor(p, off);
    qn[(size_t)row * 768 + c] = f2bf(qf / p);
}

// ---------- kernel F: projection GEMMs (z: which proj), bias, fp32 out ----------
__global__ __launch_bounds__(256) void gemm_proj(
    const u16* __restrict__ A,
    const u16* __restrict__ W1s, const float* __restrict__ b1, float* __restrict__ O1,
    const u16* __restrict__ W2s, const float* __restrict__ b2, float* __restrict__ O2)
{
    const int m0 = blockIdx.y * 128, n0 = blockIdx.x * 128;
    const int b = m0 >> 12;                  // batch of this row-block
    const u16* W = (blockIdx.z ? W2s : W1s) + (size_t)b * 589824;
    const float* bias = blockIdx.z ? b2 : b1;
    float* O = blockIdx.z ? O2 : O1;

    __shared__ u16 ldsA[4096], ldsB[4096];
    f32x4 acc[4][4] = {};
    gemm_core(A, W, 768, m0, n0, ldsA, ldsB, acc);

    const int lane = threadIdx.x & 63;
    const int wave = threadIdx.x >> 6;
    const int wm = wave >> 1, wn = wave & 1;
    const int l15 = lane & 15, l4 = lane >> 4;
#pragma unroll
    for (int i = 0; i < 4; ++i) {
#pragma unroll
        for (int j = 0; j < 4; ++j) {
            int col = n0 + wn * 64 + j * 16 + l15;
            int row = m0 + wm * 64 + i * 16 + l4 * 4;
            float bv = bias[col];
#pragma unroll
            for (int rr = 0; rr < 4; ++rr)
                O[(size_t)(row + rr) * 768 + col] = acc[i][j][rr] + bv;
        }
    }
}

extern "C" void kernel_launch(void* const* d_in, const int* in_sizes, int n_in,
                              void* d_out, int out_size, void* d_ws, size_t ws_size,
                              hipStream_t stream)
{
    const float* x     = (const float*)d_in[0];
    const float* y     = (const float*)d_in[1];
    const float* qkv_w = (const float*)d_in[2];
    const float* w1    = (const float*)d_in[3];
    const float* b1    = (const float*)d_in[4];
    const float* w2    = (const float*)d_in[5];
    const float* b2    = (const float*)d_in[6];
    float* out = (float*)d_out;

    char* ws = (char*)d_ws;
    // ws layout (total 34,639,872 B = 33.04 MB):
    //   xb  @ 0         : 25,165,824  (x bf16; dead after gemm_qkv -> reused as q')
    //   wqb @ 25165824  :  3,538,944  (qkv_w bf16; dead after gemm_qkv)
    //   w1s @ 25165824  :  4,718,592  (4 per-batch kvd-scaled W1, over dead wqb)
    //   w2s @ 29884416  :  4,718,592
    //   red @ 34603008  :     36,864  (k_sum | kv_diag | l_kv_diag)
    // qkv (bf16, 75.5 MB) lives in d_out (dead before gemm_proj writes d_out).
    u16* xb   = (u16*)(ws);
    u16* wqb  = (u16*)(ws + 25165824);
    u16* w1s  = (u16*)(ws + 25165824);
    u16* w2s  = (u16*)(ws + 29884416);
    float* red  = (float*)(ws + 34603008);
    float* ksum = red;
    float* kvd  = red + 3072;
    float* lkvd = red + 6144;
    u16* qkvb = (u16*)d_out;   // 75,497,472 B <= 100,663,296 B
    u16* qn   = xb;            // q' reuses xb region

    convert_all<<<4096, 256, 0, stream>>>(
        (const float4*)x, (const float4*)qkv_w, xb, wqb, red);

    gemm_qkv<<<dim3(18, 128), 256, 0, stream>>>(xb, wqb, qkvb);

    reduce_kv<<<768, 256, 0, stream>>>(qkvb, y, ksum, kvd, lkvd);

    scale_weights<<<1152, 256, 0, stream>>>(w1, w2, kvd, lkvd, w1s, w2s);

    norm_q<<<16384, 768, 0, stream>>>(qkvb, ksum, qn);

    gemm_proj<<<dim3(6, 128, 2), 256, 0, stream>>>(
        qn, w1s, b1, out, w2s, b2, out + 12582912);
}

// Round 3
// 434.499 us; speedup vs baseline: 1.0309x; 1.0309x over previous
//
#include <hip/hip_runtime.h>
#include <hip/hip_bf16.h>

typedef unsigned short u16;
typedef unsigned int u32;
typedef __bf16 bf16x8 __attribute__((ext_vector_type(8)));
typedef float f32x4 __attribute__((ext_vector_type(4)));

// ---------- helpers ----------
__device__ __forceinline__ float bf2f(u16 u) {
    u32 x = ((u32)u) << 16;
    return __builtin_bit_cast(float, x);
}
__device__ __forceinline__ u16 f2bf(float f) {
    u32 x = __builtin_bit_cast(u32, f);
    u32 r = (x + 0x7fffu + ((x >> 16) & 1u)) >> 16;  // RNE
    return (u16)r;
}
// delu(x) = 10*relu(x) + exp(10*min(x,0)) = x>0 ? 10x+1 : exp(10x)
__device__ __forceinline__ float delu(float x) {
    return x > 0.f ? fmaf(10.f, x, 1.f) : __expf(10.f * x);
}

// ---------- kernel A: fp32 -> bf16 for x, qkv_w; zero reduction buffers ----------
__global__ __launch_bounds__(256) void convert_all(
    const float4* __restrict__ x, const float4* __restrict__ wq,
    u16* __restrict__ xb, u16* __restrict__ wqb, float* __restrict__ red)
{
    const int NX = 3145728, NQ = 442368;
    int gid = blockIdx.x * blockDim.x + threadIdx.x;
    if (gid < 9216) red[gid] = 0.f;  // k_sum | kv_diag | l_kv_diag
    int stride = gridDim.x * blockDim.x;
    for (int i = gid; i < NX + NQ; i += stride) {
        const float4* src; u16* dst; int li;
        if (i < NX) { src = x;  dst = xb;  li = i; }
        else        { src = wq; dst = wqb; li = i - NX; }
        float4 f = src[li];
        ushort4 u;
        u.x = f2bf(f.x); u.y = f2bf(f.y); u.z = f2bf(f.z); u.w = f2bf(f.w);
        *(ushort4*)&dst[4 * (size_t)li] = u;
    }
}

// ---------- GEMM core: C[m,n] = sum_k A[m,k]*Bt[n,k], 128x128 tile, BK=32 ----------
// LDS per tile: [quad][row][8 bf16] so fragment reads are lane-contiguous
// ds_read_b128 and global_load_lds dest is wave-uniform-base + lane*16.
__device__ __forceinline__ void gemm_core(
    const u16* __restrict__ A, const u16* __restrict__ Bt,
    int K, int m0, int n0, u16* ldsA, u16* ldsB, f32x4 acc[4][4])
{
    const int tid  = threadIdx.x;
    const int lane = tid & 63;
    const int wave = tid >> 6;
    const int wm = wave >> 1, wn = wave & 1;
    const int quad = lane >> 4, r = lane & 15;

    for (int kt = 0; kt < K; kt += 32) {
#pragma unroll
        for (int it = 0; it < 2; ++it) {
            int c   = wave + 4 * it;           // chunk 0..7, wave-uniform
            int q_  = c >> 1;                  // k-quad of this chunk
            int row = ((c & 1) << 6) + lane;   // tile row 0..127
            const u16* ga = A  + (size_t)(m0 + row) * K + kt + q_ * 8;
            const u16* gb = Bt + (size_t)(n0 + row) * K + kt + q_ * 8;
            __builtin_amdgcn_global_load_lds(
                (const __attribute__((address_space(1))) u32*)(const void*)ga,
                (__attribute__((address_space(3))) u32*)(void*)&ldsA[c * 512], 16, 0, 0);
            __builtin_amdgcn_global_load_lds(
                (const __attribute__((address_space(1))) u32*)(const void*)gb,
                (__attribute__((address_space(3))) u32*)(void*)&ldsB[c * 512], 16, 0, 0);
        }
        __syncthreads();
        bf16x8 af[4], bfr[4];
#pragma unroll
        for (int i = 0; i < 4; ++i)
            af[i] = *(const bf16x8*)&ldsA[quad * 1024 + (wm * 64 + i * 16 + r) * 8];
#pragma unroll
        for (int j = 0; j < 4; ++j)
            bfr[j] = *(const bf16x8*)&ldsB[quad * 1024 + (wn * 64 + j * 16 + r) * 8];
#pragma unroll
        for (int i = 0; i < 4; ++i)
#pragma unroll
            for (int j = 0; j < 4; ++j)
                acc[i][j] = __builtin_amdgcn_mfma_f32_16x16x32_bf16(
                    af[i], bfr[j], acc[i][j], 0, 0, 0);
        __syncthreads();
    }
}

// ---------- kernel B: qkv GEMM, delu on q,k cols, bf16 out ----------
// 1-D grid (2304 blocks), XCD-swizzled: xcd = id&7 owns M-tiles [xcd*16,xcd*16+16),
// m-fast within the band so the 3.1 MB A-band stays L2-resident while B streams.
__global__ __launch_bounds__(256) void gemm_qkv(
    const u16* __restrict__ A, const u16* __restrict__ Bt, u16* __restrict__ C)
{
    const int l = blockIdx.x;
    const int xcd = l & 7, s = l >> 3;     // 288 blocks per xcd
    const int ml = s & 15, nt = s >> 4;    // nt in [0,18)
    const int m0 = (xcd * 16 + ml) * 128, n0 = nt * 128;

    __shared__ u16 ldsA[4096], ldsB[4096];
    f32x4 acc[4][4] = {};
    gemm_core(A, Bt, 768, m0, n0, ldsA, ldsB, acc);

    const int lane = threadIdx.x & 63;
    const int wave = threadIdx.x >> 6;
    const int wm = wave >> 1, wn = wave & 1;
    const int l15 = lane & 15, l4 = lane >> 4;
#pragma unroll
    for (int i = 0; i < 4; ++i) {
#pragma unroll
        for (int j = 0; j < 4; ++j) {
            int col = n0 + wn * 64 + j * 16 + l15;
            int row = m0 + wm * 64 + i * 16 + l4 * 4;
            bool isqk = col < 1536;  // q,k get delu; v passes through
#pragma unroll
            for (int rr = 0; rr < 4; ++rr) {
                float v = acc[i][j][rr];
                if (isqk) v = delu(v);
                C[(size_t)(row + rr) * 2304 + col] = f2bf(v);
            }
        }
    }
}

// ---------- kernel C: reductions over N -> k_sum, kv_diag, l_kv_diag (B,H,D) ----------
__global__ __launch_bounds__(256) void reduce_kv(
    const u16* __restrict__ qkv, const float* __restrict__ y,
    float* __restrict__ ksum, float* __restrict__ kvd, float* __restrict__ lkvd)
{
    int blk = blockIdx.x;
    int b = blk / 192, rem = blk % 192;
    int h = rem >> 4, chunk = rem & 15;
    int t = threadIdx.x;
    int d2 = t & 31, sub = t >> 5;
    int col = h * 64 + 2 * d2;

    float s_k0 = 0, s_k1 = 0, s_kv0 = 0, s_kv1 = 0, s_l0 = 0, s_l1 = 0;
    for (int i = 0; i < 32; ++i) {
        int n = chunk * 256 + sub + 8 * i;
        size_t row = (size_t)(b << 12) + n;
        u32 kk = *(const u32*)&qkv[row * 2304 + 768 + col];
        u32 vv = *(const u32*)&qkv[row * 2304 + 1536 + col];
        float2 yy = *(const float2*)&y[row * 768 + col];
        float k0 = bf2f((u16)(kk & 0xffff)), k1 = bf2f((u16)(kk >> 16));
        float v0 = bf2f((u16)(vv & 0xffff)), v1 = bf2f((u16)(vv >> 16));
        float l0 = delu(yy.x), l1 = delu(yy.y);
        s_k0 += k0;                       s_k1 += k1;
        s_kv0 = fmaf(k0, v0, s_kv0);      s_kv1 = fmaf(k1, v1, s_kv1);
        s_l0  = fmaf(l0, v0, s_l0);       s_l1  = fmaf(l1, v1, s_l1);
    }
    __shared__ float red[256][6];
    red[t][0] = s_k0; red[t][1] = s_k1; red[t][2] = s_kv0;
    red[t][3] = s_kv1; red[t][4] = s_l0; red[t][5] = s_l1;
    __syncthreads();
    if (t < 32) {
        float a0 = red[t][0], a1 = red[t][1], a2 = red[t][2];
        float a3 = red[t][3], a4 = red[t][4], a5 = red[t][5];
        for (int s = 1; s < 8; ++s) {
            a0 += red[t + 32 * s][0]; a1 += red[t + 32 * s][1];
            a2 += red[t + 32 * s][2]; a3 += red[t + 32 * s][3];
            a4 += red[t + 32 * s][4]; a5 += red[t + 32 * s][5];
        }
        int bh = b * 12 + h;
        int d = 2 * t;
        atomicAdd(&ksum[bh * 64 + d],     a0);
        atomicAdd(&ksum[bh * 64 + d + 1], a1);
        atomicAdd(&kvd[bh * 64 + d],      a2 * 0.125f);
        atomicAdd(&kvd[bh * 64 + d + 1],  a3 * 0.125f);
        atomicAdd(&lkvd[bh * 64 + d],     a4 * 0.125f);
        atomicAdd(&lkvd[bh * 64 + d + 1], a5 * 0.125f);
    }
}

// ---------- kernel D: fold kv_diag / l_kv_diag into per-batch scaled weights ----------
// w1s[b][o][c] = w1[o][c] * kvd[b, c>>6, c&63]   (bf16), same for w2s/lkvd.
__global__ __launch_bounds__(256) void scale_weights(
    const float* __restrict__ w1, const float* __restrict__ w2,
    const float* __restrict__ kvd, const float* __restrict__ lkvd,
    u16* __restrict__ w1s, u16* __restrict__ w2s)
{
    const int NITEM = 1179648;  // 2 tensors * 4 batches * 768 * 192 quads
    int gid = blockIdx.x * blockDim.x + threadIdx.x;
    int stride = gridDim.x * blockDim.x;
    for (int i = gid; i < NITEM; i += stride) {
        int t = i / 589824, r = i % 589824;
        int b = r / 147456, rr = r % 147456;
        int o = rr / 192, c = (rr % 192) * 4;
        const float* w = t ? w2 : w1;
        const float* dg = t ? lkvd : kvd;
        u16* dst = t ? w2s : w1s;
        float4 wf = *(const float4*)&w[o * 768 + c];
        float4 sf = *(const float4*)&dg[(b * 12 + (c >> 6)) * 64 + (c & 63)];
        ushort4 u;
        u.x = f2bf(wf.x * sf.x); u.y = f2bf(wf.y * sf.y);
        u.z = f2bf(wf.z * sf.z); u.w = f2bf(wf.w * sf.w);
        *(ushort4*)&dst[(size_t)b * 589824 + o * 768 + c] = u;
    }
}

// ---------- kernel E: q' = q * norm  (bf16) ----------
// block = 768 threads = 12 waves; wave == head; lane == d channel.
__global__ __launch_bounds__(768) void norm_q(
    const u16* __restrict__ qkv, const float* __restrict__ ksum,
    u16* __restrict__ qn)
{
    int row = blockIdx.x;
    int c = threadIdx.x;
    int h = c >> 6, d = c & 63;
    int b = row >> 12;
    int bh = b * 12 + h;
    float qf = bf2f(qkv[(size_t)row * 2304 + c]);   // q (already delu'd)
    float ks = ksum[bh * 64 + d] + 1e-10f;
    float p = qf * ks;
#pragma unroll
    for (int off = 32; off; off >>= 1) p += __shfl_xor(p, off);
    qn[(size_t)row * 768 + c] = f2bf(qf / p);
}

// ---------- kernel F: projection GEMMs, bias, fp32 out ----------
// 1-D grid (1536 blocks), XCD-swizzled. Each XCD's 16-M-tile band (2048 rows)
// lies inside ONE batch -> it touches exactly one W1s/W2s slice (2.4 MB, L2-resident).
__global__ __launch_bounds__(256) void gemm_proj(
    const u16* __restrict__ A,
    const u16* __restrict__ W1s, const float* __restrict__ b1, float* __restrict__ O1,
    const u16* __restrict__ W2s, const float* __restrict__ b2, float* __restrict__ O2)
{
    const int l = blockIdx.x;
    const int xcd = l & 7, s = l >> 3;     // 192 blocks per xcd
    const int ml = s & 15, c_ = s >> 4;    // c_ in [0,12): (n,z) combo
    const int nt = c_ % 6, z = c_ / 6;
    const int m0 = (xcd * 16 + ml) * 128, n0 = nt * 128;
    const int b = m0 >> 12;                // batch of this row-block
    const u16* W = (z ? W2s : W1s) + (size_t)b * 589824;
    const float* bias = z ? b2 : b1;
    float* O = z ? O2 : O1;

    __shared__ u16 ldsA[4096], ldsB[4096];
    f32x4 acc[4][4] = {};
    gemm_core(A, W, 768, m0, n0, ldsA, ldsB, acc);

    const int lane = threadIdx.x & 63;
    const int wave = threadIdx.x >> 6;
    const int wm = wave >> 1, wn = wave & 1;
    const int l15 = lane & 15, l4 = lane >> 4;
#pragma unroll
    for (int i = 0; i < 4; ++i) {
#pragma unroll
        for (int j = 0; j < 4; ++j) {
            int col = n0 + wn * 64 + j * 16 + l15;
            int row = m0 + wm * 64 + i * 16 + l4 * 4;
            float bv = bias[col];
#pragma unroll
            for (int rr = 0; rr < 4; ++rr)
                O[(size_t)(row + rr) * 768 + col] = acc[i][j][rr] + bv;
        }
    }
}

extern "C" void kernel_launch(void* const* d_in, const int* in_sizes, int n_in,
                              void* d_out, int out_size, void* d_ws, size_t ws_size,
                              hipStream_t stream)
{
    const float* x     = (const float*)d_in[0];
    const float* y     = (const float*)d_in[1];
    const float* qkv_w = (const float*)d_in[2];
    const float* w1    = (const float*)d_in[3];
    const float* b1    = (const float*)d_in[4];
    const float* w2    = (const float*)d_in[5];
    const float* b2    = (const float*)d_in[6];
    float* out = (float*)d_out;

    char* ws = (char*)d_ws;
    // ws layout (total 34,639,872 B = 33.04 MB):
    //   xb  @ 0         : 25,165,824  (x bf16; dead after gemm_qkv -> reused as q')
    //   wqb @ 25165824  :  3,538,944  (qkv_w bf16; dead after gemm_qkv)
    //   w1s @ 25165824  :  4,718,592  (4 per-batch kvd-scaled W1, over dead wqb)
    //   w2s @ 29884416  :  4,718,592
    //   red @ 34603008  :     36,864  (k_sum | kv_diag | l_kv_diag)
    // qkv (bf16, 75.5 MB) lives in d_out (dead before gemm_proj writes d_out).
    u16* xb   = (u16*)(ws);
    u16* wqb  = (u16*)(ws + 25165824);
    u16* w1s  = (u16*)(ws + 25165824);
    u16* w2s  = (u16*)(ws + 29884416);
    float* red  = (float*)(ws + 34603008);
    float* ksum = red;
    float* kvd  = red + 3072;
    float* lkvd = red + 6144;
    u16* qkvb = (u16*)d_out;   // 75,497,472 B <= 100,663,296 B
    u16* qn   = xb;            // q' reuses xb region

    convert_all<<<4096, 256, 0, stream>>>(
        (const float4*)x, (const float4*)qkv_w, xb, wqb, red);

    gemm_qkv<<<2304, 256, 0, stream>>>(xb, wqb, qkvb);

    reduce_kv<<<768, 256, 0, stream>>>(qkvb, y, ksum, kvd, lkvd);

    scale_weights<<<1152, 256, 0, stream>>>(w1, w2, kvd, lkvd, w1s, w2s);

    norm_q<<<16384, 768, 0, stream>>>(qkvb, ksum, qn);

    gemm_proj<<<1536, 256, 0, stream>>>(
        qn, w1s, b1, out, w2s, b2, out + 12582912);
}